// Round 15
// baseline (160.165 us; speedup 1.0000x reference)
//
#include <hip/hip_runtime.h>

// Camera back-projection R15: single compute phase + single store phase.
//
// R13 family (~45us kernel) writes each block's 8192 elems in 4 chunks ->
// per-ix-row store pieces of 128B (25% of each 512B span) -> L2 evicts
// sparse dirty lines; plus 9 barriers/block. R15 computes the FULL
// 16ix x 4iy x 128iz block region into one 33KB LDS tile (16 gathers/thread
// in flight, no intervening barriers), then stores once:
//   - per ix-row the store region is 4iy x 128iz = 2KB CONTIGUOUS;
//     each wave store instr = 1KB contiguous run;
//   - with slab-major ordering (R13), 32 concurrent blocks complete full
//     64KB ix-rows densely -> dense dirty-line eviction, long DRAM runs;
//   - 2 barriers/block total (was 9).
// LDS = tile 33,792 + U 4,352 + V 2,112 = 40,256B < 40,960 -> 4 blocks/CU
// x 8 waves = 32 waves/CU. Tile stride 132 floats: both b128 phases at the
// 8-words/bank floor (stride mod 32 = 4, same math as TS=36).
//
// Numerics (absmax 0.0 every round): exact IEEE '/' + rintf half-to-even in
// the reference's op order; U = ui<<2|uok<<15 (ushort), V = vi*1920|vok<<31;
// offset = ((U&0x7FFF)+V)&0xFFFFF, valid = sign(V & U<<16); epilogue
// max(fma(-128,|zc-d|,1),0) == 1-128*min(|zc-d|,1/128) exactly; zc via exact
// fma; d>0 folds into the truncation branch (zc >= 1.70).

#define RES  128
#define IMG  480
#define TS   132    // result tile row stride (floats), 128 iz + 4 pad
#define US   136    // U slab row stride (ushorts)
#define VS   132    // V slab row stride (uints)

__global__ __launch_bounds__(512, 8) void cbp_main(
    const float* __restrict__ depth, const float* __restrict__ fl,
    const float* __restrict__ cam_dist, float* __restrict__ out, int N)
{
    __shared__ __align__(16) float          s_tile[64 * TS];  // 33,792 B
    __shared__ __align__(16) unsigned short s_U[16 * US];     //  4,352 B
    __shared__ __align__(16) unsigned       s_V[4 * VS];      //  2,112 B

    const int b = blockIdx.x;
    int n, rblk;
    if (N == 16) {                  // XCD-local: 2 depth images per XCD's L2
        const int xcd = b & 7, i = b >> 3;
        n = xcd * 2 + (i >> 8);
        rblk = i & 255;
    } else { n = b >> 8; rblk = b & 255; }
    const int ixg = rblk >> 5;      // 16-ix group (0..7), slab-major:
    const int iyg = rblk & 31;      // concurrent blocks tile one 1MB ix-slab
    const int l   = threadIdx.x;
    const float flv = fl[n];
    const float cd  = cam_dist[n];

    // ---- in-block tables: 5 exact IEEE divisions per thread ----
#pragma unroll
    for (int k = 0; k < 4; ++k) {   // U slab: 16 ix rows x 128 iz
        const int e   = l + 512 * k;
        const int row = e >> 7, izt = e & 127;
        const float zc = cd - ((izt + 0.5f) / 128.0f - 0.5f);
        const float x  = (ixg * 16 + row + 0.5f) / 128.0f - 0.5f;
        const float u  = (flv * x) / zc + 239.5f;            // exact IEEE div
        const int   ui = (int)fminf(fmaxf(rintf(u), 0.0f), 479.0f);
        const unsigned uok = (u >= 0.0f) && (u <= 479.0f);
        s_U[row * US + izt] = (unsigned short)((ui << 2) | (uok << 15));
    }
    {   // V slab: 4 iy rows x 128 iz (512 entries, one per thread)
        const int iyt = l >> 7, izt = l & 127;
        const float zc = cd - ((izt + 0.5f) / 128.0f - 0.5f);
        const float y  = (iyg * 4 + iyt + 0.5f) / 128.0f - 0.5f;
        const float v  = (flv * y) / zc + 239.5f;            // exact IEEE div
        const int   vi = (int)fminf(fmaxf(rintf(v), 0.0f), 479.0f);
        const unsigned vok = (v >= 0.0f) && (v <= 479.0f) && (zc > 0.0f);
        s_V[iyt * VS + izt] = (unsigned)(vi * (IMG * 4)) | (vok << 31);
    }
    __syncthreads();

    // ---- compute phase: 16 elems/thread, all gathers free to overlap ----
    const int ix_l = l & 15, iy_l = (l >> 4) & 3, w = l >> 6;  // w: 0..7
    const int trow = ix_l * 4 + iy_l;
    const char* __restrict__ dbase = (const char*)(depth + (size_t)n * (IMG * IMG));

#pragma unroll
    for (int g = 0; g < 4; ++g) {
        const int jq  = w * 4 + g;           // iz quad (0..31), wave-uniform
        const int izc = jq * 4;
        const ushort4 pu4 = *(const ushort4*)&s_U[ix_l * US + izc];
        const uint4   pv4 = *(const uint4*)&s_V[iy_l * VS + izc];
        const unsigned pua[4] = {pu4.x, pu4.y, pu4.z, pu4.w};
        const unsigned pva[4] = {pv4.x, pv4.y, pv4.z, pv4.w};
        float4 rr; float* rp = &rr.x;
#pragma unroll
        for (int j = 0; j < 4; ++j) {
            const int   iz = izc + j;
            const float z  = fmaf((float)iz + 0.5f, 0.0078125f, -0.5f); // exact
            const float zc = cd - z;
            const unsigned off = ((pua[j] & 0x7FFFu) + pva[j]) & 0xFFFFFu;
            const float d  = *(const float*)(dbase + off);   // cache-hot gather
            const bool ok  = (int)(pva[j] & (pua[j] << 16)) < 0;
            const float v  = fmaxf(fmaf(-128.0f, fabsf(zc - d), 1.0f), 0.0f);
            rp[j] = ok ? v : 0.0f;
        }
        *(float4*)&s_tile[trow * TS + izc] = rr;   // b128, bank floor
    }
    __syncthreads();

    // ---- store phase: 4 float4/thread; wave instr = 1KB contiguous run;
    //      per ix-row the block writes 2KB contiguous ----
    const size_t obase = ((size_t)((n << 7) + ixg * 16) << 7 | (iyg * 4)) << 7;
#pragma unroll
    for (int s = 0; s < 4; ++s) {
        const int f   = l + 512 * s;          // float4 index, 0..2047
        const int e   = f << 2;               // element index, 0..8191
        const int ix2 = e >> 9;               // 0..15
        const int rem = e & 511;              // iy2*128 + iz
        const float4 val = *(const float4*)&s_tile[(ix2 * 4 + (rem >> 7)) * TS + (rem & 127)];
        *(float4*)&out[obase + ((size_t)ix2 << 14) + rem] = val;
    }
}

extern "C" void kernel_launch(void* const* d_in, const int* in_sizes, int n_in,
                              void* d_out, int out_size, void* d_ws, size_t ws_size,
                              hipStream_t stream) {
    const float* depth = (const float*)d_in[0];
    const float* fl    = (const float*)d_in[1];
    const float* cd    = (const float*)d_in[2];
    float* out         = (float*)d_out;

    const int N = in_sizes[1];                     // fl is (N,1)
    cbp_main<<<N * 256, 512, 0, stream>>>(depth, fl, cd, out, N);
}

// Round 16
// 157.924 us; speedup vs baseline: 1.0142x; 1.0142x over previous
//
#include <hip/hip_runtime.h>

// Camera back-projection FINAL (= R13 champion, 157.3us bench / ~46us kernel).
//
// Structure: in-block bit-exact U/V tables in LDS, lanes = 16ix x 4iy
// (row-riding gathers, ~4-8 lines/instr), 32-iz chunks transposed through a
// 9.2KB LDS tile at the b128 bank floor, software-pipelined gathers across
// the store phase, slab-major write ordering (concurrent blocks tile one
// contiguous 1MB ix-slab), XCD-local depth (2 images per XCD's 4MB L2),
// 8 blocks/CU = 32 waves/CU.
//
// Measured plateau (R4-R15): every structural variant lands at 45-60us
// kernel; single-factor interventions (gather latency/geometry, DRAM run
// length, NT stores, barrier count, table fusion) all within +-2%. Composite
// model: 0.37 cyc/elem HBM-write floor + 0.25-0.45 cyc/elem divergent-gather
// TA processing + ~0.1 LDS/VALU = 0.7-0.9 vs measured 0.84 cyc/elem.
//
// Numerics (absmax 0.0 every round): exact IEEE '/' + rintf half-to-even in
// the reference's op order; U = ui<<2|uok<<15, V = vi*1920|vok<<31;
// offset = ((U&0x7FFF)+V)&0xFFFFF, valid = sign(V & U<<16); epilogue
// max(fma(-128,|zc-d|,1),0) == 1-128*min(|zc-d|,1/128) exactly; zc inline
// via exact fma; d>0 folds into the truncation branch (zc >= 1.70).

#define RES  128
#define IMG  480
#define TS   36     // result tile row stride (floats)
#define US   136    // U slab row stride (ushorts)
#define VS   132    // V slab row stride (uints)

template<int C>
__device__ __forceinline__ void compute_chunk(
    float* __restrict__ r,
    const unsigned short* __restrict__ sU,
    const unsigned* __restrict__ sV,
    const char* __restrict__ dbase,
    float cd, int ix_l, int iy_l, int w)
{
#pragma unroll
    for (int g = 0; g < 2; ++g) {
        const int jq  = w * 2 + g;           // iz quad slot (0..7)
        const int izc = C * 32 + jq * 4;     // global iz of quad
        const ushort4 pu4 = *(const ushort4*)&sU[ix_l * US + izc];
        const uint4   pv4 = *(const uint4*)&sV[iy_l * VS + izc];
        const unsigned pua[4] = {pu4.x, pu4.y, pu4.z, pu4.w};
        const unsigned pva[4] = {pv4.x, pv4.y, pv4.z, pv4.w};
#pragma unroll
        for (int j = 0; j < 4; ++j) {
            const int   iz = izc + j;
            const float z  = fmaf((float)iz + 0.5f, 0.0078125f, -0.5f); // exact
            const float zc = cd - z;
            const unsigned off = ((pua[j] & 0x7FFFu) + pva[j]) & 0xFFFFFu;
            const float d  = *(const float*)(dbase + off);   // cache-hot gather
            const bool ok  = (int)(pva[j] & (pua[j] << 16)) < 0;
            const float v  = fmaxf(fmaf(-128.0f, fabsf(zc - d), 1.0f), 0.0f);
            r[g * 4 + j] = ok ? v : 0.0f;
        }
    }
}

__global__ __launch_bounds__(256, 8) void cbp_main(
    const float* __restrict__ depth, const float* __restrict__ fl,
    const float* __restrict__ cam_dist, float* __restrict__ out, int N)
{
    __shared__ __align__(16) float          s_tile[64 * TS];  // 9216 B
    __shared__ __align__(16) unsigned short s_U[16 * US];     // 4352 B
    __shared__ __align__(16) unsigned       s_V[4 * VS];      // 2112 B

    const int b = blockIdx.x;
    int n, rblk;
    if (N == 16) {                  // XCD-local: 2 depth images per XCD's L2
        const int xcd = b & 7, i = b >> 3;
        n = xcd * 2 + (i >> 8);
        rblk = i & 255;
    } else { n = b >> 8; rblk = b & 255; }
    const int ixg = rblk >> 5;      // 16-ix group (0..7), slab-major:
    const int iyg = rblk & 31;      // concurrent blocks tile one 1MB ix-slab
    const int l   = threadIdx.x;
    const float flv = fl[n];
    const float cd  = cam_dist[n];

    // ---- in-block tables: 10 exact IEEE divisions per thread ----
#pragma unroll
    for (int k = 0; k < 8; ++k) {   // U slab: 16 ix rows x 128 iz
        const int e   = l + 256 * k;
        const int row = e >> 7, izt = e & 127;
        const float zc = cd - ((izt + 0.5f) / 128.0f - 0.5f);
        const float x  = (ixg * 16 + row + 0.5f) / 128.0f - 0.5f;
        const float u  = (flv * x) / zc + 239.5f;            // exact IEEE div
        const int   ui = (int)fminf(fmaxf(rintf(u), 0.0f), 479.0f);
        const unsigned uok = (u >= 0.0f) && (u <= 479.0f);
        s_U[row * US + izt] = (unsigned short)((ui << 2) | (uok << 15));
    }
#pragma unroll
    for (int k = 0; k < 2; ++k) {   // V slab: 4 iy rows x 128 iz
        const int e   = l + 256 * k;
        const int iyt = e >> 7, izt = e & 127;
        const float zc = cd - ((izt + 0.5f) / 128.0f - 0.5f);
        const float y  = (iyg * 4 + iyt + 0.5f) / 128.0f - 0.5f;
        const float v  = (flv * y) / zc + 239.5f;            // exact IEEE div
        const int   vi = (int)fminf(fmaxf(rintf(v), 0.0f), 479.0f);
        const unsigned vok = (v >= 0.0f) && (v <= 479.0f) && (zc > 0.0f);
        s_V[iyt * VS + izt] = (unsigned)(vi * (IMG * 4)) | (vok << 31);
    }
    __syncthreads();

    const int ix_l = l & 15, iy_l = (l >> 4) & 3, w = l >> 6;
    const int trow = ix_l * 4 + iy_l;
    const char* __restrict__ dbase = (const char*)(depth + (size_t)n * (IMG * IMG));
    const size_t obase = ((size_t)((n << 7) + ixg * 16) << 7 | (iyg * 4)) << 7;

    float r[8];                     // pipelined chunk results (2 float4)
    compute_chunk<0>(r, s_U, s_V, dbase, cd, ix_l, iy_l, w);

#pragma unroll
    for (int c = 0; c < 4; ++c) {
        __syncthreads();            // tile free (prev store-phase reads done)
        *(float4*)&s_tile[trow * TS + (w * 2) * 4]     = *(const float4*)&r[0];
        *(float4*)&s_tile[trow * TS + (w * 2 + 1) * 4] = *(const float4*)&r[4];
        __syncthreads();            // tile full

        // issue next chunk's gathers now; they overlap the store phase below
        if (c == 0) compute_chunk<1>(r, s_U, s_V, dbase, cd, ix_l, iy_l, w);
        else if (c == 1) compute_chunk<2>(r, s_U, s_V, dbase, cd, ix_l, iy_l, w);
        else if (c == 2) compute_chunk<3>(r, s_U, s_V, dbase, cd, ix_l, iy_l, w);

        // store: 2 float4/thread; wave instr = 8 x 128B pieces
#pragma unroll
        for (int s = 0; s < 2; ++s) {
            const int f  = l + 256 * s;          // 0..511
            const int rw = f >> 3, q = f & 7;
            const float4 val = *(const float4*)&s_tile[rw * TS + q * 4];
            const int ix2 = rw >> 2, iy2 = rw & 3;
            *(float4*)&out[obase + ((size_t)ix2 << 14) + (iy2 << 7) + c * 32 + q * 4] = val;
        }
    }
}

extern "C" void kernel_launch(void* const* d_in, const int* in_sizes, int n_in,
                              void* d_out, int out_size, void* d_ws, size_t ws_size,
                              hipStream_t stream) {
    const float* depth = (const float*)d_in[0];
    const float* fl    = (const float*)d_in[1];
    const float* cd    = (const float*)d_in[2];
    float* out         = (float*)d_out;

    const int N = in_sizes[1];                     // fl is (N,1)
    cbp_main<<<N * 256, 256, 0, stream>>>(depth, fl, cd, out, N);
}